// Round 16
// baseline (151.149 us; speedup 1.0000x reference)
//
#include <hip/hip_runtime.h>

#define NN 50000
#define NE 800000
#define DIN 256
#define F1 96
#define F2 48
#define F3 24
#define EPSL 1e-5f
#define BKN 256     // nodes per bucket
#define NBUK 196    // ceil(NN/256)
#define SB 256      // scatter/hist blocks
#define EPB 3125    // edges per block (SB*EPB == NE exactly)
#define SORTCAP 6144

using bf16x8 = __attribute__((ext_vector_type(8))) short;
using f32x4 = __attribute__((ext_vector_type(4))) float;

__device__ __forceinline__ unsigned short f2b(float f) {
    unsigned u = __float_as_uint(f);
    unsigned r = (u + 0x7FFF + ((u >> 16) & 1)) >> 16;
    return (unsigned short)r;
}
__device__ __forceinline__ float b2f(unsigned short h) {
    return __uint_as_float((unsigned)h << 16);
}
__device__ __forceinline__ void unpk8(uint4 u, float* f) {
    f[0] = __uint_as_float(u.x << 16);
    f[1] = __uint_as_float(u.x & 0xFFFF0000u);
    f[2] = __uint_as_float(u.y << 16);
    f[3] = __uint_as_float(u.y & 0xFFFF0000u);
    f[4] = __uint_as_float(u.z << 16);
    f[5] = __uint_as_float(u.z & 0xFFFF0000u);
    f[6] = __uint_as_float(u.w << 16);
    f[7] = __uint_as_float(u.w & 0xFFFF0000u);
}

// ---------------- edge-index access (int32 or int64 storage) ----------------
__device__ __forceinline__ int ld_src(const int* __restrict__ ei, int is64, int e) {
    return is64 ? ei[2 * e] : ei[e];
}
__device__ __forceinline__ int ld_dst(const int* __restrict__ ei, int is64, int e) {
    return is64 ? ei[2 * NE + 2 * e] : ei[NE + e];
}
// parallel int64-detection: wave 0 probes 64 odd words with one load + ballot
__device__ __forceinline__ void detect64_par(const int* __restrict__ ei, int t,
                                             int* sflag) {
    if (t < 64) {
        unsigned long long m = __ballot(ei[2 * t + 1] == 0);
        if (t == 0) *sflag = (__popcll(m) >= 60) ? 1 : 0;
    }
}

// --- merged prep + histogram: blocks 0-11 W1 frags, 12 BN consts, 13+ hist ---
__global__ __launch_bounds__(512) void k_prephist(
    const float* __restrict__ W1, ushort* __restrict__ Wh, ushort* __restrict__ Wl,
    const float* __restrict__ b1, const float* __restrict__ g1,
    const float* __restrict__ bb1, const float* __restrict__ m1,
    const float* __restrict__ v1, const float* __restrict__ b2,
    const float* __restrict__ g2, const float* __restrict__ bb2,
    const float* __restrict__ m2, const float* __restrict__ v2,
    const float* __restrict__ b3, const float* __restrict__ g3,
    const float* __restrict__ bb3, const float* __restrict__ m3,
    const float* __restrict__ v3, float* __restrict__ sc, float* __restrict__ sh,
    const int* __restrict__ ei, int* __restrict__ bh) {
    if (blockIdx.x < 12) {
        if (threadIdx.x >= 256) return;
        int gid = blockIdx.x * 256 + threadIdx.x;
        int l = gid & 63;
        int sw = gid >> 6;
        int s = sw & 7;
        int w = sw >> 3;
        int col = w * 16 + (l & 15);
        int kbase = s * 32 + (l >> 4) * 8;
        ushort hi[8], lo[8];
#pragma unroll
        for (int j = 0; j < 8; j++) {
            float v = W1[(size_t)(kbase + j) * F1 + col];
            ushort h = f2b(v);
            hi[j] = h;
            lo[j] = f2b(v - b2f(h));
        }
        *(uint4*)&Wh[(size_t)gid * 8] = *(uint4*)hi;
        *(uint4*)&Wl[(size_t)gid * 8] = *(uint4*)lo;
    } else if (blockIdx.x == 12) {
        int t = threadIdx.x;
        if (t < F1) {
            float s = g1[t] * rsqrtf(v1[t] + EPSL);
            sc[t] = s;
            sh[t] = bb1[t] - m1[t] * s + b1[t] * s;
        } else if (t < F1 + F2) {
            int f = t - F1;
            float s = g2[f] * rsqrtf(v2[f] + EPSL);
            sc[t] = s;
            sh[t] = bb2[f] - m2[f] * s + b2[f] * s;
        } else if (t < F1 + F2 + F3) {
            int f = t - F1 - F2;
            float s = g3[f] * rsqrtf(v3[f] + EPSL);
            sc[t] = s;
            sh[t] = bb3[f] - m3[f] * s + b3[f] * s;
        }
    } else {
        __shared__ int hist[NBUK];
        __shared__ int sflag;
        int blk = blockIdx.x - 13, t = threadIdx.x;
        detect64_par(ei, t, &sflag);
        for (int i = t; i < NBUK; i += 512) hist[i] = 0;
        __syncthreads();
        int is64 = sflag;
        int e0 = blk * EPB;
        for (int i = t; i < EPB; i += 512) {
            int d = ld_dst(ei, is64, e0 + i);
            atomicAdd(&hist[d >> 8], 1);
        }
        __syncthreads();
        for (int i = t; i < NBUK; i += 512) bh[blk * NBUK + i] = hist[i];
    }
}

// --- per-(block,bucket) bases (TRANSPOSED: bb[blk][bucket]) + bucket bases ---
__global__ __launch_bounds__(256) void k_scanB3(const int* __restrict__ bh,
                                                int* __restrict__ bb,
                                                int* __restrict__ btxg) {
    __shared__ int sA[256], ex[256], sB[256];
    int b = blockIdx.x, t = threadIdx.x;
    int v = 0;
    if (t < NBUK) {
        for (int blk = 0; blk < SB; blk++) v += bh[blk * NBUK + t];
    }
    sA[t] = v;
    __syncthreads();
    for (int off = 1; off < 256; off <<= 1) {
        int x = (t >= off) ? sA[t - off] : 0;
        __syncthreads();
        sA[t] += x;
        __syncthreads();
    }
    ex[t] = sA[t] - v;
    __syncthreads();
    int btx_b = ex[b];
    int w = bh[t * NBUK + b];
    sB[t] = w;
    __syncthreads();
    for (int off = 1; off < 256; off <<= 1) {
        int x = (t >= off) ? sB[t - off] : 0;
        __syncthreads();
        sB[t] += x;
        __syncthreads();
    }
    bb[t * NBUK + b] = btx_b + sB[t] - w;  // transposed for coalesced scatter read
    if (t == 0) btxg[b] = btx_b;
    if (b == 0 && t == 0) btxg[NBUK] = NE;
}

// ------- scatter edges into bucket regions via LDS cursors -------
__global__ __launch_bounds__(512) void k_scatterB(const int* __restrict__ ei,
                                                  const int* __restrict__ bb,
                                                  uint* __restrict__ csr) {
    __shared__ int cur[NBUK];
    __shared__ int sflag;
    int blk = blockIdx.x, t = threadIdx.x;
    detect64_par(ei, t, &sflag);
    for (int i = t; i < NBUK; i += 512) cur[i] = bb[blk * NBUK + i];  // coalesced
    __syncthreads();
    int is64 = sflag;
    int e0 = blk * EPB;
    for (int i = t; i < EPB; i += 512) {
        int e = e0 + i;
        int d = ld_dst(ei, is64, e);
        int s = ld_src(ei, is64, e);
        int pos = atomicAdd(&cur[d >> 8], 1);
        csr[pos] = ((uint)(d & (BKN - 1)) << 16) | (uint)s;
    }
}

// --- per-bucket compaction (to ushort csr2) + rowstart + dis (block-local) ---
__global__ __launch_bounds__(256) void k_sortb(const int* __restrict__ btxg,
                                               const uint* __restrict__ csr,
                                               ushort* __restrict__ csr2,
                                               int* __restrict__ rowstart,
                                               float* __restrict__ dis) {
    __shared__ uint ent[SORTCAP];
    __shared__ int cnt2[BKN], exs[BKN], cur[BKN];
    int b = blockIdx.x, t = threadIdx.x;
    int base = btxg[b];
    int cntE = btxg[b + 1] - base;
    if (cntE > SORTCAP) cntE = SORTCAP;  // statistically impossible
    cnt2[t] = 0;
    __syncthreads();
    for (int i = t; i < cntE; i += 256) {
        uint v = csr[base + i];
        ent[i] = v;
        atomicAdd(&cnt2[v >> 16], 1);
    }
    __syncthreads();
    int v = cnt2[t];
    exs[t] = v;
    __syncthreads();
    for (int off = 1; off < 256; off <<= 1) {
        int x = (t >= off) ? exs[t - off] : 0;
        __syncthreads();
        exs[t] += x;
        __syncthreads();
    }
    int excl = exs[t] - v;
    int n = b * BKN + t;
    if (n < NN) {
        rowstart[n] = base + excl;
        dis[n] = rsqrtf((float)v + 1.0f);
    }
    if (b == NBUK - 1 && t == 0) rowstart[NN] = NE;
    cur[t] = excl;
    __syncthreads();
    for (int i = t; i < cntE; i += 256) {
        uint v2 = ent[i];
        int p = atomicAdd(&cur[v2 >> 16], 1);
        csr2[base + p] = (ushort)(v2 & 0xFFFFu);
    }
}

// --- GEMM1: fused LN @ W1, single-bf16 A x (W_hi + W_lo) MFMA, ·dis -> bf16 ---
__global__ __launch_bounds__(384) void k_gemm1m(
    const float* __restrict__ x, const float* __restrict__ dis,
    const float* __restrict__ ln_g, const float* __restrict__ ln_b,
    const ushort* __restrict__ Wh, const ushort* __restrict__ Wl,
    ushort* __restrict__ outb) {
    __shared__ ushort Ah[2048 * 8];  // 32KB, xor-swizzled, 4 row-groups
    int tid = threadIdx.x;
    int l = tid & 63;
    int w = tid >> 6;
    int brow = blockIdx.x * 64;

    bf16x8 Bh[8], Bl[8];
#pragma unroll
    for (int s = 0; s < 8; s++) {
        int gid = (w * 8 + s) * 64 + l;
        Bh[s] = *(const bf16x8*)&Wh[(size_t)gid * 8];
        Bl[s] = *(const bf16x8*)&Wl[(size_t)gid * 8];
    }

    for (int t = tid; t < 2048; t += 384) {
        int r = t >> 5;
        int c = t & 31;
        int row = brow + r;
        float4 v0 = make_float4(0.f, 0.f, 0.f, 0.f), v1 = v0;
        if (row < NN) {
            const float4* xp = (const float4*)(x + (size_t)row * DIN + c * 8);
            v0 = xp[0];
            v1 = xp[1];
        }
        float s = v0.x + v0.y + v0.z + v0.w + v1.x + v1.y + v1.z + v1.w;
        float q = v0.x * v0.x + v0.y * v0.y + v0.z * v0.z + v0.w * v0.w +
                  v1.x * v1.x + v1.y * v1.y + v1.z * v1.z + v1.w * v1.w;
#pragma unroll
        for (int off = 1; off < 32; off <<= 1) {
            s += __shfl_xor(s, off);
            q += __shfl_xor(q, off);
        }
        float m = s * (1.f / 256.f);
        float rs = rsqrtf(q * (1.f / 256.f) - m * m + EPSL);
        ushort hi[8];
        const float4* gp = (const float4*)(ln_g + c * 8);
        const float4* bp = (const float4*)(ln_b + c * 8);
        float4 g0 = gp[0], g1 = gp[1];
        float4 b0 = bp[0], b1 = bp[1];
        hi[0] = f2b((v0.x - m) * rs * g0.x + b0.x);
        hi[1] = f2b((v0.y - m) * rs * g0.y + b0.y);
        hi[2] = f2b((v0.z - m) * rs * g0.z + b0.z);
        hi[3] = f2b((v0.w - m) * rs * g0.w + b0.w);
        hi[4] = f2b((v1.x - m) * rs * g1.x + b1.x);
        hi[5] = f2b((v1.y - m) * rs * g1.y + b1.y);
        hi[6] = f2b((v1.z - m) * rs * g1.z + b1.z);
        hi[7] = f2b((v1.w - m) * rs * g1.w + b1.w);
        int sidx = c >> 2, lh = c & 3, rg = r >> 4;
        int slot = (rg * 8 + sidx) * 64 + lh * 16 + (r & 15);
        int byte_off = (slot * 16) ^ ((c & 7) << 4);
        *(uint4*)((char*)Ah + byte_off) = *(uint4*)hi;
    }
    __syncthreads();

    f32x4 acc[4] = {{0.f, 0.f, 0.f, 0.f},
                    {0.f, 0.f, 0.f, 0.f},
                    {0.f, 0.f, 0.f, 0.f},
                    {0.f, 0.f, 0.f, 0.f}};
#pragma unroll
    for (int s = 0; s < 8; s++) {
        int key = ((s * 4 + (l >> 4)) & 7) << 4;
#pragma unroll
        for (int rg = 0; rg < 4; rg++) {
            int boff = (((rg * 8 + s) * 64 + l) * 16) ^ key;
            bf16x8 a = *(const bf16x8*)((const char*)Ah + boff);
            acc[rg] = __builtin_amdgcn_mfma_f32_16x16x32_bf16(a, Bl[s], acc[rg], 0, 0, 0);
            acc[rg] = __builtin_amdgcn_mfma_f32_16x16x32_bf16(a, Bh[s], acc[rg], 0, 0, 0);
        }
    }

    int colg = w * 16 + (l & 15);
    int rbase = (l >> 4) * 4;
#pragma unroll
    for (int rg = 0; rg < 4; rg++) {
#pragma unroll
        for (int i = 0; i < 4; i++) {
            int row = brow + rg * 16 + rbase + i;
            if (row < NN) outb[(size_t)row * F1 + colg] = f2b(acc[rg][i] * dis[row]);
        }
    }
}

// ----- CSR gather agg (bf16, 16B/request, 8-edge unroll) -> bf16 -----
template <int G>
__global__ __launch_bounds__(256) void k_agg(const ushort* __restrict__ hb,
                                             const ushort* __restrict__ csr2,
                                             const int* __restrict__ rowstart,
                                             const float* __restrict__ dis,
                                             const float* __restrict__ bnsc,
                                             const float* __restrict__ bnsh,
                                             ushort* __restrict__ outb) {
    int t = blockIdx.x * blockDim.x + threadIdx.x;
    if (t >= NN * G) return;
    int n = t / G;
    int g = t - n * G;
    const uint4* hrow = (const uint4*)hb;
    int e0 = rowstart[n], e1 = rowstart[n + 1];
    float acc[8] = {};
    int e = e0;
    for (; e + 8 <= e1; e += 8) {
        uint4 u[8];
#pragma unroll
        for (int k = 0; k < 8; k++) u[k] = hrow[(size_t)csr2[e + k] * G + g];
#pragma unroll
        for (int k = 0; k < 8; k++) {
            float f[8];
            unpk8(u[k], f);
#pragma unroll
            for (int j = 0; j < 8; j++) acc[j] += f[j];
        }
    }
    for (; e < e1; e++) {
        uint4 u = hrow[(size_t)csr2[e] * G + g];
        float f[8];
        unpk8(u, f);
#pragma unroll
        for (int j = 0; j < 8; j++) acc[j] += f[j];
    }
    {
        uint4 u = hrow[(size_t)n * G + g];
        float f[8];
        unpk8(u, f);
#pragma unroll
        for (int j = 0; j < 8; j++) acc[j] += f[j];
    }
    float d = dis[n];
    const float4 sc0 = *(const float4*)&bnsc[g * 8];
    const float4 sc1 = *(const float4*)&bnsc[g * 8 + 4];
    const float4 sh0 = *(const float4*)&bnsh[g * 8];
    const float4 sh1 = *(const float4*)&bnsh[g * 8 + 4];
    ushort o[8];
    o[0] = f2b(fmaxf(acc[0] * d * sc0.x + sh0.x, 0.f));
    o[1] = f2b(fmaxf(acc[1] * d * sc0.y + sh0.y, 0.f));
    o[2] = f2b(fmaxf(acc[2] * d * sc0.z + sh0.z, 0.f));
    o[3] = f2b(fmaxf(acc[3] * d * sc0.w + sh0.w, 0.f));
    o[4] = f2b(fmaxf(acc[4] * d * sc1.x + sh1.x, 0.f));
    o[5] = f2b(fmaxf(acc[5] * d * sc1.y + sh1.y, 0.f));
    o[6] = f2b(fmaxf(acc[6] * d * sc1.z + sh1.z, 0.f));
    o[7] = f2b(fmaxf(acc[7] * d * sc1.w + sh1.w, 0.f));
    *(uint4*)&outb[(size_t)n * (G * 8) + g * 8] = *(uint4*)o;
}

// ------- GEMM2: agg1[NN,96](bf16) @ W2[96,48] -> bf16·dis (vectorized stage) ----
__global__ __launch_bounds__(256) void k_gemm2(const ushort* __restrict__ A,
                                               const float* __restrict__ W,
                                               const float* __restrict__ dis,
                                               ushort* __restrict__ outb) {
    __shared__ float At[F1][68];
    __shared__ float Ws[F1][F2];
    int tid = threadIdx.x;
    int brow = blockIdx.x * 64;
#pragma unroll
    for (int i = 0; i < 3; i++) {
        int idx = tid + i * 256;  // < 768 = 64 rows x 12 uint4
        int r = idx / 12;
        int cg8 = idx - r * 12;
        int row = brow + r;
        float f[8];
        if (row < NN) {
            uint4 u = *(const uint4*)&A[(size_t)row * F1 + cg8 * 8];
            unpk8(u, f);
        } else {
#pragma unroll
            for (int j = 0; j < 8; j++) f[j] = 0.f;
        }
#pragma unroll
        for (int j = 0; j < 8; j++) At[cg8 * 8 + j][r] = f[j];
    }
#pragma unroll
    for (int i = 0; i < 18; i++) {
        int idx = tid + i * 256;
        Ws[idx / F2][idx % F2] = W[idx];
    }
    __syncthreads();
    int rg = tid >> 4;
    int cg = tid & 15;
    float acc[4][3] = {};
#pragma unroll 4
    for (int k = 0; k < F1; k++) {
        float4 a = *(const float4*)&At[k][rg * 4];
        float b[3];
        b[0] = Ws[k][cg * 3];
        b[1] = Ws[k][cg * 3 + 1];
        b[2] = Ws[k][cg * 3 + 2];
#pragma unroll
        for (int j = 0; j < 3; j++) {
            acc[0][j] += a.x * b[j];
            acc[1][j] += a.y * b[j];
            acc[2][j] += a.z * b[j];
            acc[3][j] += a.w * b[j];
        }
    }
#pragma unroll
    for (int i = 0; i < 4; i++) {
        int row = brow + rg * 4 + i;
        if (row < NN) {
            float dsc = dis[row];
            ushort* o = outb + (size_t)row * F2 + cg * 3;
#pragma unroll
            for (int j = 0; j < 3; j++) o[j] = f2b(acc[i][j] * dsc);
        }
    }
}

// ------- GEMM3: agg2[NN,48](bf16) @ W3[48,24] -> bf16·dis (vectorized stage) ----
__global__ __launch_bounds__(256) void k_gemm3(const ushort* __restrict__ A,
                                               const float* __restrict__ W,
                                               const float* __restrict__ dis,
                                               ushort* __restrict__ outb) {
    __shared__ float At[F2][132];
    __shared__ float Ws[F2][F3];
    int tid = threadIdx.x;
    int brow = blockIdx.x * 128;
#pragma unroll
    for (int i = 0; i < 3; i++) {
        int idx = tid + i * 256;  // < 768 = 128 rows x 6 uint4
        int r = idx / 6;
        int cg8 = idx - r * 6;
        int row = brow + r;
        float f[8];
        if (row < NN) {
            uint4 u = *(const uint4*)&A[(size_t)row * F2 + cg8 * 8];
            unpk8(u, f);
        } else {
#pragma unroll
            for (int j = 0; j < 8; j++) f[j] = 0.f;
        }
#pragma unroll
        for (int j = 0; j < 8; j++) At[cg8 * 8 + j][r] = f[j];
    }
#pragma unroll
    for (int i = 0; i < 5; i++) {
        int idx = tid + i * 256;
        if (idx < F2 * F3) Ws[idx / F3][idx % F3] = W[idx];
    }
    __syncthreads();
    int rg = tid >> 3;
    int cg = tid & 7;
    float acc[4][3] = {};
#pragma unroll 4
    for (int k = 0; k < F2; k++) {
        float4 a = *(const float4*)&At[k][rg * 4];
        float b[3];
        b[0] = Ws[k][cg * 3];
        b[1] = Ws[k][cg * 3 + 1];
        b[2] = Ws[k][cg * 3 + 2];
#pragma unroll
        for (int j = 0; j < 3; j++) {
            acc[0][j] += a.x * b[j];
            acc[1][j] += a.y * b[j];
            acc[2][j] += a.z * b[j];
            acc[3][j] += a.w * b[j];
        }
    }
#pragma unroll
    for (int i = 0; i < 4; i++) {
        int row = brow + rg * 4 + i;
        if (row < NN) {
            float dsc = dis[row];
            ushort* o = outb + (size_t)row * F3 + cg * 3;
#pragma unroll
            for (int j = 0; j < 3; j++) o[j] = f2b(acc[i][j] * dsc);
        }
    }
}

// -- fused agg<3> (fp32 in LDS) + BN + ReLU + fc1 + LN + ReLU + fc2 -> out --
__global__ __launch_bounds__(256) void k_aggcls(
    const ushort* __restrict__ hb, const ushort* __restrict__ csr2,
    const int* __restrict__ rowstart, const float* __restrict__ dis,
    const float* __restrict__ bnsc, const float* __restrict__ bnsh,
    const float* __restrict__ fc1W, const float* __restrict__ fc1b,
    const float* __restrict__ lng, const float* __restrict__ lnb,
    const float* __restrict__ fc2W, const float* __restrict__ fc2b,
    float* __restrict__ out) {
    __shared__ float hs_l[64][25];
    __shared__ float sW1[24 * 12], sW2[12 * 8], sb1[12], sg[12], sb[12], sb2[8];
    int tid = threadIdx.x;
    int brow = blockIdx.x * 64;
    for (int i = tid; i < 288; i += 256) sW1[i] = fc1W[i];
    if (tid < 96) sW2[tid] = fc2W[tid];
    if (tid < 12) {
        sb1[tid] = fc1b[tid];
        sg[tid] = lng[tid];
        sb[tid] = lnb[tid];
    }
    if (tid < 8) sb2[tid] = fc2b[tid];
    if (tid < 192) {
        int r = tid / 3;
        int g = tid - r * 3;
        int n = brow + r;
        if (n < NN) {
            const uint4* hrow = (const uint4*)hb;
            int e0 = rowstart[n], e1 = rowstart[n + 1];
            float acc[8] = {};
            int e = e0;
            for (; e + 8 <= e1; e += 8) {
                uint4 u[8];
#pragma unroll
                for (int k = 0; k < 8; k++) u[k] = hrow[(size_t)csr2[e + k] * 3 + g];
#pragma unroll
                for (int k = 0; k < 8; k++) {
                    float f[8];
                    unpk8(u[k], f);
#pragma unroll
                    for (int j = 0; j < 8; j++) acc[j] += f[j];
                }
            }
            for (; e < e1; e++) {
                uint4 u = hrow[(size_t)csr2[e] * 3 + g];
                float f[8];
                unpk8(u, f);
#pragma unroll
                for (int j = 0; j < 8; j++) acc[j] += f[j];
            }
            {
                uint4 u = hrow[(size_t)n * 3 + g];
                float f[8];
                unpk8(u, f);
#pragma unroll
                for (int j = 0; j < 8; j++) acc[j] += f[j];
            }
            float d = dis[n];
#pragma unroll
            for (int j = 0; j < 8; j++) {
                int q = g * 8 + j;
                hs_l[r][q] = fmaxf(acc[j] * d * bnsc[q] + bnsh[q], 0.f);
            }
        }
    }
    __syncthreads();
    if (tid >= 64) return;
    int n = brow + tid;
    if (n >= NN) return;
    float z[12];
#pragma unroll
    for (int j = 0; j < 12; j++) {
        float a = sb1[j];
#pragma unroll
        for (int k = 0; k < 24; k++) a += hs_l[tid][k] * sW1[k * 12 + j];
        z[j] = a;
    }
    float s = 0.f, q = 0.f;
#pragma unroll
    for (int j = 0; j < 12; j++) {
        s += z[j];
        q += z[j] * z[j];
    }
    float m = s * (1.f / 12.f);
    float var = q * (1.f / 12.f) - m * m;
    float rs = rsqrtf(var + EPSL);
#pragma unroll
    for (int j = 0; j < 12; j++) z[j] = fmaxf((z[j] - m) * rs * sg[j] + sb[j], 0.f);
    float o[8];
#pragma unroll
    for (int c = 0; c < 8; c++) {
        float a = sb2[c];
#pragma unroll
        for (int j = 0; j < 12; j++) a += z[j] * sW2[j * 8 + c];
        o[c] = a;
    }
    float4* op = (float4*)(out + (size_t)n * 8);
    op[0] = make_float4(o[0], o[1], o[2], o[3]);
    op[1] = make_float4(o[4], o[5], o[6], o[7]);
}

// ---------------- launch ----------------
extern "C" void kernel_launch(void* const* d_in, const int* in_sizes, int n_in,
                              void* d_out, int out_size, void* d_ws, size_t ws_size,
                              hipStream_t stream) {
    const float* x = (const float*)d_in[0];
    const int* ei = (const int*)d_in[1];
    const float* ln_g = (const float*)d_in[2];
    const float* ln_b = (const float*)d_in[3];
    const float* W1 = (const float*)d_in[4];
    const float* b1 = (const float*)d_in[5];
    const float* bn1_g = (const float*)d_in[6];
    const float* bn1_b = (const float*)d_in[7];
    const float* bn1_m = (const float*)d_in[8];
    const float* bn1_v = (const float*)d_in[9];
    const float* W2 = (const float*)d_in[10];
    const float* b2 = (const float*)d_in[11];
    const float* bn2_g = (const float*)d_in[12];
    const float* bn2_b = (const float*)d_in[13];
    const float* bn2_m = (const float*)d_in[14];
    const float* bn2_v = (const float*)d_in[15];
    const float* W3 = (const float*)d_in[16];
    const float* b3 = (const float*)d_in[17];
    const float* bn3_g = (const float*)d_in[18];
    const float* bn3_b = (const float*)d_in[19];
    const float* bn3_m = (const float*)d_in[20];
    const float* bn3_v = (const float*)d_in[21];
    const float* fc1_W = (const float*)d_in[22];
    const float* fc1_b = (const float*)d_in[23];
    const float* lnc_g = (const float*)d_in[24];
    const float* lnc_b = (const float*)d_in[25];
    const float* fc2_W = (const float*)d_in[26];
    const float* fc2_b = (const float*)d_in[27];

    char* w = (char*)d_ws;
    auto alloc = [&](size_t bytes) {
        char* p = w;
        w += (bytes + 255) & ~(size_t)255;
        return p;
    };
    int* bh = (int*)alloc((size_t)SB * NBUK * 4);
    int* bb = (int*)alloc((size_t)SB * NBUK * 4);  // [blk][bucket]
    int* btxg = (int*)alloc((NBUK + 1) * 4);
    int* rowstart = (int*)alloc((NN + 1) * 4);
    float* dis = (float*)alloc(NN * 4);
    float* bnsc = (float*)alloc(1024);
    float* bnsh = (float*)alloc(1024);
    uint* csr = (uint*)alloc((size_t)NE * 4);      // staged (d_local, src) pairs
    ushort* csr2 = (ushort*)alloc((size_t)NE * 2); // compacted src-only
    ushort* hb = (ushort*)alloc((size_t)NN * F1 * 2);  // gemm outputs (·dis)
    ushort* ag = (ushort*)alloc((size_t)NN * F1 * 2);  // agg outputs
    ushort* Wh = (ushort*)alloc(3072 * 8 * 2);
    ushort* Wl = (ushort*)alloc(3072 * 8 * 2);

    k_prephist<<<13 + SB, 512, 0, stream>>>(W1, Wh, Wl, b1, bn1_g, bn1_b, bn1_m, bn1_v,
                                            b2, bn2_g, bn2_b, bn2_m, bn2_v, b3, bn3_g,
                                            bn3_b, bn3_m, bn3_v, bnsc, bnsh, ei, bh);
    k_scanB3<<<NBUK, 256, 0, stream>>>(bh, bb, btxg);
    k_scatterB<<<SB, 512, 0, stream>>>(ei, bb, csr);
    k_sortb<<<NBUK, 256, 0, stream>>>(btxg, csr, csr2, rowstart, dis);
    k_gemm1m<<<(NN + 63) / 64, 384, 0, stream>>>(x, dis, ln_g, ln_b, Wh, Wl, hb);
    k_agg<12><<<(NN * 12 + 255) / 256, 256, 0, stream>>>(hb, csr2, rowstart, dis, bnsc,
                                                         bnsh, ag);
    k_gemm2<<<(NN + 63) / 64, 256, 0, stream>>>(ag, W2, dis, hb);
    k_agg<6><<<(NN * 6 + 255) / 256, 256, 0, stream>>>(hb, csr2, rowstart, dis,
                                                       bnsc + F1, bnsh + F1, ag);
    k_gemm3<<<(NN + 127) / 128, 256, 0, stream>>>(ag, W3, dis, hb);
    k_aggcls<<<(NN + 63) / 64, 256, 0, stream>>>(hb, csr2, rowstart, dis,
                                                 bnsc + F1 + F2, bnsh + F1 + F2, fc1_W,
                                                 fc1_b, lnc_g, lnc_b, fc2_W, fc2_b,
                                                 (float*)d_out);
}

// Round 17
// 143.726 us; speedup vs baseline: 1.0516x; 1.0516x over previous
//
#include <hip/hip_runtime.h>

#define NN 50000
#define NE 800000
#define DIN 256
#define F1 96
#define F2 48
#define F3 24
#define EPSL 1e-5f
#define BKN 256     // nodes per bucket
#define NBUK 196    // ceil(NN/256)
#define SB 256      // scatter/hist blocks
#define EPB 3125    // edges per block (SB*EPB == NE exactly)
#define SORTCAP 6144

using bf16x8 = __attribute__((ext_vector_type(8))) short;
using f32x4 = __attribute__((ext_vector_type(4))) float;

__device__ __forceinline__ unsigned short f2b(float f) {
    unsigned u = __float_as_uint(f);
    unsigned r = (u + 0x7FFF + ((u >> 16) & 1)) >> 16;
    return (unsigned short)r;
}
__device__ __forceinline__ float b2f(unsigned short h) {
    return __uint_as_float((unsigned)h << 16);
}
__device__ __forceinline__ void unpk8(uint4 u, float* f) {
    f[0] = __uint_as_float(u.x << 16);
    f[1] = __uint_as_float(u.x & 0xFFFF0000u);
    f[2] = __uint_as_float(u.y << 16);
    f[3] = __uint_as_float(u.y & 0xFFFF0000u);
    f[4] = __uint_as_float(u.z << 16);
    f[5] = __uint_as_float(u.z & 0xFFFF0000u);
    f[6] = __uint_as_float(u.w << 16);
    f[7] = __uint_as_float(u.w & 0xFFFF0000u);
}

// ---------------- edge-index access (int32 or int64 storage) ----------------
__device__ __forceinline__ int ld_src(const int* __restrict__ ei, int is64, int e) {
    return is64 ? ei[2 * e] : ei[e];
}
__device__ __forceinline__ int ld_dst(const int* __restrict__ ei, int is64, int e) {
    return is64 ? ei[2 * NE + 2 * e] : ei[NE + e];
}
// parallel int64-detection: wave 0 probes 64 odd words with one load + ballot
__device__ __forceinline__ void detect64_par(const int* __restrict__ ei, int t,
                                             int* sflag) {
    if (t < 64) {
        unsigned long long m = __ballot(ei[2 * t + 1] == 0);
        if (t == 0) *sflag = (__popcll(m) >= 60) ? 1 : 0;
    }
}

// --- merged prep + histogram: blocks 0-11 W1 frags, 12 BN consts, 13+ hist ---
__global__ __launch_bounds__(512) void k_prephist(
    const float* __restrict__ W1, ushort* __restrict__ Wh, ushort* __restrict__ Wl,
    const float* __restrict__ b1, const float* __restrict__ g1,
    const float* __restrict__ bb1, const float* __restrict__ m1,
    const float* __restrict__ v1, const float* __restrict__ b2,
    const float* __restrict__ g2, const float* __restrict__ bb2,
    const float* __restrict__ m2, const float* __restrict__ v2,
    const float* __restrict__ b3, const float* __restrict__ g3,
    const float* __restrict__ bb3, const float* __restrict__ m3,
    const float* __restrict__ v3, float* __restrict__ sc, float* __restrict__ sh,
    const int* __restrict__ ei, int* __restrict__ bh) {
    if (blockIdx.x < 12) {
        if (threadIdx.x >= 256) return;
        int gid = blockIdx.x * 256 + threadIdx.x;
        int l = gid & 63;
        int sw = gid >> 6;
        int s = sw & 7;
        int w = sw >> 3;
        int col = w * 16 + (l & 15);
        int kbase = s * 32 + (l >> 4) * 8;
        ushort hi[8], lo[8];
#pragma unroll
        for (int j = 0; j < 8; j++) {
            float v = W1[(size_t)(kbase + j) * F1 + col];
            ushort h = f2b(v);
            hi[j] = h;
            lo[j] = f2b(v - b2f(h));
        }
        *(uint4*)&Wh[(size_t)gid * 8] = *(uint4*)hi;
        *(uint4*)&Wl[(size_t)gid * 8] = *(uint4*)lo;
    } else if (blockIdx.x == 12) {
        int t = threadIdx.x;
        if (t < F1) {
            float s = g1[t] * rsqrtf(v1[t] + EPSL);
            sc[t] = s;
            sh[t] = bb1[t] - m1[t] * s + b1[t] * s;
        } else if (t < F1 + F2) {
            int f = t - F1;
            float s = g2[f] * rsqrtf(v2[f] + EPSL);
            sc[t] = s;
            sh[t] = bb2[f] - m2[f] * s + b2[f] * s;
        } else if (t < F1 + F2 + F3) {
            int f = t - F1 - F2;
            float s = g3[f] * rsqrtf(v3[f] + EPSL);
            sc[t] = s;
            sh[t] = bb3[f] - m3[f] * s + b3[f] * s;
        }
    } else {
        __shared__ int hist[NBUK];
        __shared__ int sflag;
        int blk = blockIdx.x - 13, t = threadIdx.x;
        detect64_par(ei, t, &sflag);
        for (int i = t; i < NBUK; i += 512) hist[i] = 0;
        __syncthreads();
        int is64 = sflag;
        int e0 = blk * EPB;
        for (int i = t; i < EPB; i += 512) {
            int d = ld_dst(ei, is64, e0 + i);
            atomicAdd(&hist[d >> 8], 1);
        }
        __syncthreads();
        for (int i = t; i < NBUK; i += 512) bh[blk * NBUK + i] = hist[i];
    }
}

// --- per-(block,bucket) bases (TRANSPOSED: bb[blk][bucket]) + bucket bases ---
__global__ __launch_bounds__(256) void k_scanB3(const int* __restrict__ bh,
                                                int* __restrict__ bb,
                                                int* __restrict__ btxg) {
    __shared__ int sA[256], ex[256], sB[256];
    int b = blockIdx.x, t = threadIdx.x;
    int v = 0;
    if (t < NBUK) {
        for (int blk = 0; blk < SB; blk++) v += bh[blk * NBUK + t];
    }
    sA[t] = v;
    __syncthreads();
    for (int off = 1; off < 256; off <<= 1) {
        int x = (t >= off) ? sA[t - off] : 0;
        __syncthreads();
        sA[t] += x;
        __syncthreads();
    }
    ex[t] = sA[t] - v;
    __syncthreads();
    int btx_b = ex[b];
    int w = bh[t * NBUK + b];
    sB[t] = w;
    __syncthreads();
    for (int off = 1; off < 256; off <<= 1) {
        int x = (t >= off) ? sB[t - off] : 0;
        __syncthreads();
        sB[t] += x;
        __syncthreads();
    }
    bb[t * NBUK + b] = btx_b + sB[t] - w;  // transposed for coalesced scatter read
    if (t == 0) btxg[b] = btx_b;
    if (b == 0 && t == 0) btxg[NBUK] = NE;
}

// ------- scatter edges into bucket regions via LDS cursors -------
__global__ __launch_bounds__(512) void k_scatterB(const int* __restrict__ ei,
                                                  const int* __restrict__ bb,
                                                  uint* __restrict__ csr) {
    __shared__ int cur[NBUK];
    __shared__ int sflag;
    int blk = blockIdx.x, t = threadIdx.x;
    detect64_par(ei, t, &sflag);
    for (int i = t; i < NBUK; i += 512) cur[i] = bb[blk * NBUK + i];  // coalesced
    __syncthreads();
    int is64 = sflag;
    int e0 = blk * EPB;
    for (int i = t; i < EPB; i += 512) {
        int e = e0 + i;
        int d = ld_dst(ei, is64, e);
        int s = ld_src(ei, is64, e);
        int pos = atomicAdd(&cur[d >> 8], 1);
        csr[pos] = ((uint)(d & (BKN - 1)) << 16) | (uint)s;
    }
}

// --- per-bucket compaction (to ushort csr2) + rowstart + dis (block-local) ---
__global__ __launch_bounds__(256) void k_sortb(const int* __restrict__ btxg,
                                               const uint* __restrict__ csr,
                                               ushort* __restrict__ csr2,
                                               int* __restrict__ rowstart,
                                               float* __restrict__ dis) {
    __shared__ uint ent[SORTCAP];
    __shared__ int cnt2[BKN], exs[BKN], cur[BKN];
    int b = blockIdx.x, t = threadIdx.x;
    int base = btxg[b];
    int cntE = btxg[b + 1] - base;
    if (cntE > SORTCAP) cntE = SORTCAP;  // statistically impossible
    cnt2[t] = 0;
    __syncthreads();
    for (int i = t; i < cntE; i += 256) {
        uint v = csr[base + i];
        ent[i] = v;
        atomicAdd(&cnt2[v >> 16], 1);
    }
    __syncthreads();
    int v = cnt2[t];
    exs[t] = v;
    __syncthreads();
    for (int off = 1; off < 256; off <<= 1) {
        int x = (t >= off) ? exs[t - off] : 0;
        __syncthreads();
        exs[t] += x;
        __syncthreads();
    }
    int excl = exs[t] - v;
    int n = b * BKN + t;
    if (n < NN) {
        rowstart[n] = base + excl;
        dis[n] = rsqrtf((float)v + 1.0f);
    }
    if (b == NBUK - 1 && t == 0) rowstart[NN] = NE;
    cur[t] = excl;
    __syncthreads();
    for (int i = t; i < cntE; i += 256) {
        uint v2 = ent[i];
        int p = atomicAdd(&cur[v2 >> 16], 1);
        csr2[base + p] = (ushort)(v2 & 0xFFFFu);
    }
}

// --- GEMM1: fused LN @ W1, bf16 MFMA, K split across 12 waves -> bf16·dis ---
// waves 0-5: cols 16w, k in [0,128); waves 6-11: same cols, k in [128,256).
// Partial accumulators reduced through Ah LDS (dead after MFMA).
__global__ __launch_bounds__(768) void k_gemm1m(
    const float* __restrict__ x, const float* __restrict__ dis,
    const float* __restrict__ ln_g, const float* __restrict__ ln_b,
    const ushort* __restrict__ Wh, const ushort* __restrict__ Wl,
    ushort* __restrict__ outb) {
    __shared__ ushort Ah[2048 * 8];  // 32KB, xor-swizzled, 4 row-groups
    int tid = threadIdx.x;
    int l = tid & 63;
    int w = tid >> 6;  // 0..11
    int wc = w % 6;    // col-tile
    int kh = w / 6;    // k-half
    int brow = blockIdx.x * 64;

    bf16x8 Bh[4], Bl[4];
#pragma unroll
    for (int si = 0; si < 4; si++) {
        int s = kh * 4 + si;
        int gid = (wc * 8 + s) * 64 + l;
        Bh[si] = *(const bf16x8*)&Wh[(size_t)gid * 8];
        Bl[si] = *(const bf16x8*)&Wl[(size_t)gid * 8];
    }

    for (int t = tid; t < 2048; t += 768) {
        int r = t >> 5;
        int c = t & 31;
        int row = brow + r;
        float4 v0 = make_float4(0.f, 0.f, 0.f, 0.f), v1 = v0;
        if (row < NN) {
            const float4* xp = (const float4*)(x + (size_t)row * DIN + c * 8);
            v0 = xp[0];
            v1 = xp[1];
        }
        float s = v0.x + v0.y + v0.z + v0.w + v1.x + v1.y + v1.z + v1.w;
        float q = v0.x * v0.x + v0.y * v0.y + v0.z * v0.z + v0.w * v0.w +
                  v1.x * v1.x + v1.y * v1.y + v1.z * v1.z + v1.w * v1.w;
#pragma unroll
        for (int off = 1; off < 32; off <<= 1) {
            s += __shfl_xor(s, off);
            q += __shfl_xor(q, off);
        }
        float m = s * (1.f / 256.f);
        float rs = rsqrtf(q * (1.f / 256.f) - m * m + EPSL);
        ushort hi[8];
        const float4* gp = (const float4*)(ln_g + c * 8);
        const float4* bp = (const float4*)(ln_b + c * 8);
        float4 g0 = gp[0], g1 = gp[1];
        float4 b0 = bp[0], b1 = bp[1];
        hi[0] = f2b((v0.x - m) * rs * g0.x + b0.x);
        hi[1] = f2b((v0.y - m) * rs * g0.y + b0.y);
        hi[2] = f2b((v0.z - m) * rs * g0.z + b0.z);
        hi[3] = f2b((v0.w - m) * rs * g0.w + b0.w);
        hi[4] = f2b((v1.x - m) * rs * g1.x + b1.x);
        hi[5] = f2b((v1.y - m) * rs * g1.y + b1.y);
        hi[6] = f2b((v1.z - m) * rs * g1.z + b1.z);
        hi[7] = f2b((v1.w - m) * rs * g1.w + b1.w);
        int sidx = c >> 2, lh = c & 3, rg = r >> 4;
        int slot = (rg * 8 + sidx) * 64 + lh * 16 + (r & 15);
        int byte_off = (slot * 16) ^ ((c & 7) << 4);
        *(uint4*)((char*)Ah + byte_off) = *(uint4*)hi;
    }
    __syncthreads();

    f32x4 acc[4] = {{0.f, 0.f, 0.f, 0.f},
                    {0.f, 0.f, 0.f, 0.f},
                    {0.f, 0.f, 0.f, 0.f},
                    {0.f, 0.f, 0.f, 0.f}};
#pragma unroll
    for (int si = 0; si < 4; si++) {
        int s = kh * 4 + si;
        int key = ((s * 4 + (l >> 4)) & 7) << 4;
#pragma unroll
        for (int rg = 0; rg < 4; rg++) {
            int boff = (((rg * 8 + s) * 64 + l) * 16) ^ key;
            bf16x8 a = *(const bf16x8*)((const char*)Ah + boff);
            acc[rg] = __builtin_amdgcn_mfma_f32_16x16x32_bf16(a, Bl[si], acc[rg], 0, 0, 0);
            acc[rg] = __builtin_amdgcn_mfma_f32_16x16x32_bf16(a, Bh[si], acc[rg], 0, 0, 0);
        }
    }

    // reduce k-halves through LDS (reuse Ah; element-strided = conflict-free)
    __syncthreads();  // all Ah reads done
    float* red = (float*)Ah;  // 384 lanes x 16 floats = 24KB < 32KB
    if (kh == 1) {
#pragma unroll
        for (int rg = 0; rg < 4; rg++)
#pragma unroll
            for (int i = 0; i < 4; i++)
                red[(wc * 64 + l) + 384 * (rg * 4 + i)] = acc[rg][i];
    }
    __syncthreads();
    if (kh == 0) {
#pragma unroll
        for (int rg = 0; rg < 4; rg++)
#pragma unroll
            for (int i = 0; i < 4; i++)
                acc[rg][i] += red[(wc * 64 + l) + 384 * (rg * 4 + i)];
        int colg = wc * 16 + (l & 15);
        int rbase = (l >> 4) * 4;
#pragma unroll
        for (int rg = 0; rg < 4; rg++) {
#pragma unroll
            for (int i = 0; i < 4; i++) {
                int row = brow + rg * 16 + rbase + i;
                if (row < NN) outb[(size_t)row * F1 + colg] = f2b(acc[rg][i] * dis[row]);
            }
        }
    }
}

// ----- CSR gather agg (bf16, 16B/request, 8-edge unroll) -> bf16 -----
template <int G>
__global__ __launch_bounds__(256) void k_agg(const ushort* __restrict__ hb,
                                             const ushort* __restrict__ csr2,
                                             const int* __restrict__ rowstart,
                                             const float* __restrict__ dis,
                                             const float* __restrict__ bnsc,
                                             const float* __restrict__ bnsh,
                                             ushort* __restrict__ outb) {
    int t = blockIdx.x * blockDim.x + threadIdx.x;
    if (t >= NN * G) return;
    int n = t / G;
    int g = t - n * G;
    const uint4* hrow = (const uint4*)hb;
    int e0 = rowstart[n], e1 = rowstart[n + 1];
    float acc[8] = {};
    int e = e0;
    for (; e + 8 <= e1; e += 8) {
        uint4 u[8];
#pragma unroll
        for (int k = 0; k < 8; k++) u[k] = hrow[(size_t)csr2[e + k] * G + g];
#pragma unroll
        for (int k = 0; k < 8; k++) {
            float f[8];
            unpk8(u[k], f);
#pragma unroll
            for (int j = 0; j < 8; j++) acc[j] += f[j];
        }
    }
    for (; e < e1; e++) {
        uint4 u = hrow[(size_t)csr2[e] * G + g];
        float f[8];
        unpk8(u, f);
#pragma unroll
        for (int j = 0; j < 8; j++) acc[j] += f[j];
    }
    {
        uint4 u = hrow[(size_t)n * G + g];
        float f[8];
        unpk8(u, f);
#pragma unroll
        for (int j = 0; j < 8; j++) acc[j] += f[j];
    }
    float d = dis[n];
    const float4 sc0 = *(const float4*)&bnsc[g * 8];
    const float4 sc1 = *(const float4*)&bnsc[g * 8 + 4];
    const float4 sh0 = *(const float4*)&bnsh[g * 8];
    const float4 sh1 = *(const float4*)&bnsh[g * 8 + 4];
    ushort o[8];
    o[0] = f2b(fmaxf(acc[0] * d * sc0.x + sh0.x, 0.f));
    o[1] = f2b(fmaxf(acc[1] * d * sc0.y + sh0.y, 0.f));
    o[2] = f2b(fmaxf(acc[2] * d * sc0.z + sh0.z, 0.f));
    o[3] = f2b(fmaxf(acc[3] * d * sc0.w + sh0.w, 0.f));
    o[4] = f2b(fmaxf(acc[4] * d * sc1.x + sh1.x, 0.f));
    o[5] = f2b(fmaxf(acc[5] * d * sc1.y + sh1.y, 0.f));
    o[6] = f2b(fmaxf(acc[6] * d * sc1.z + sh1.z, 0.f));
    o[7] = f2b(fmaxf(acc[7] * d * sc1.w + sh1.w, 0.f));
    *(uint4*)&outb[(size_t)n * (G * 8) + g * 8] = *(uint4*)o;
}

// ------- GEMM2: agg1[NN,96](bf16) @ W2[96,48] -> bf16·dis (vectorized stage) ----
__global__ __launch_bounds__(256) void k_gemm2(const ushort* __restrict__ A,
                                               const float* __restrict__ W,
                                               const float* __restrict__ dis,
                                               ushort* __restrict__ outb) {
    __shared__ float At[F1][68];
    __shared__ float Ws[F1][F2];
    int tid = threadIdx.x;
    int brow = blockIdx.x * 64;
#pragma unroll
    for (int i = 0; i < 3; i++) {
        int idx = tid + i * 256;  // < 768 = 64 rows x 12 uint4
        int r = idx / 12;
        int cg8 = idx - r * 12;
        int row = brow + r;
        float f[8];
        if (row < NN) {
            uint4 u = *(const uint4*)&A[(size_t)row * F1 + cg8 * 8];
            unpk8(u, f);
        } else {
#pragma unroll
            for (int j = 0; j < 8; j++) f[j] = 0.f;
        }
#pragma unroll
        for (int j = 0; j < 8; j++) At[cg8 * 8 + j][r] = f[j];
    }
#pragma unroll
    for (int i = 0; i < 18; i++) {
        int idx = tid + i * 256;
        Ws[idx / F2][idx % F2] = W[idx];
    }
    __syncthreads();
    int rg = tid >> 4;
    int cg = tid & 15;
    float acc[4][3] = {};
#pragma unroll 4
    for (int k = 0; k < F1; k++) {
        float4 a = *(const float4*)&At[k][rg * 4];
        float b[3];
        b[0] = Ws[k][cg * 3];
        b[1] = Ws[k][cg * 3 + 1];
        b[2] = Ws[k][cg * 3 + 2];
#pragma unroll
        for (int j = 0; j < 3; j++) {
            acc[0][j] += a.x * b[j];
            acc[1][j] += a.y * b[j];
            acc[2][j] += a.z * b[j];
            acc[3][j] += a.w * b[j];
        }
    }
#pragma unroll
    for (int i = 0; i < 4; i++) {
        int row = brow + rg * 4 + i;
        if (row < NN) {
            float dsc = dis[row];
            ushort* o = outb + (size_t)row * F2 + cg * 3;
#pragma unroll
            for (int j = 0; j < 3; j++) o[j] = f2b(acc[i][j] * dsc);
        }
    }
}

// ------- GEMM3: agg2[NN,48](bf16) @ W3[48,24] -> bf16·dis (vectorized stage) ----
__global__ __launch_bounds__(256) void k_gemm3(const ushort* __restrict__ A,
                                               const float* __restrict__ W,
                                               const float* __restrict__ dis,
                                               ushort* __restrict__ outb) {
    __shared__ float At[F2][132];
    __shared__ float Ws[F2][F3];
    int tid = threadIdx.x;
    int brow = blockIdx.x * 128;
#pragma unroll
    for (int i = 0; i < 3; i++) {
        int idx = tid + i * 256;  // < 768 = 128 rows x 6 uint4
        int r = idx / 6;
        int cg8 = idx - r * 6;
        int row = brow + r;
        float f[8];
        if (row < NN) {
            uint4 u = *(const uint4*)&A[(size_t)row * F2 + cg8 * 8];
            unpk8(u, f);
        } else {
#pragma unroll
            for (int j = 0; j < 8; j++) f[j] = 0.f;
        }
#pragma unroll
        for (int j = 0; j < 8; j++) At[cg8 * 8 + j][r] = f[j];
    }
#pragma unroll
    for (int i = 0; i < 5; i++) {
        int idx = tid + i * 256;
        if (idx < F2 * F3) Ws[idx / F3][idx % F3] = W[idx];
    }
    __syncthreads();
    int rg = tid >> 3;
    int cg = tid & 7;
    float acc[4][3] = {};
#pragma unroll 4
    for (int k = 0; k < F2; k++) {
        float4 a = *(const float4*)&At[k][rg * 4];
        float b[3];
        b[0] = Ws[k][cg * 3];
        b[1] = Ws[k][cg * 3 + 1];
        b[2] = Ws[k][cg * 3 + 2];
#pragma unroll
        for (int j = 0; j < 3; j++) {
            acc[0][j] += a.x * b[j];
            acc[1][j] += a.y * b[j];
            acc[2][j] += a.z * b[j];
            acc[3][j] += a.w * b[j];
        }
    }
#pragma unroll
    for (int i = 0; i < 4; i++) {
        int row = brow + rg * 4 + i;
        if (row < NN) {
            float dsc = dis[row];
            ushort* o = outb + (size_t)row * F3 + cg * 3;
#pragma unroll
            for (int j = 0; j < 3; j++) o[j] = f2b(acc[i][j] * dsc);
        }
    }
}

// -- fused agg<3> (fp32 in LDS) + BN + ReLU + fc1 + LN + ReLU + fc2 -> out --
__global__ __launch_bounds__(256) void k_aggcls(
    const ushort* __restrict__ hb, const ushort* __restrict__ csr2,
    const int* __restrict__ rowstart, const float* __restrict__ dis,
    const float* __restrict__ bnsc, const float* __restrict__ bnsh,
    const float* __restrict__ fc1W, const float* __restrict__ fc1b,
    const float* __restrict__ lng, const float* __restrict__ lnb,
    const float* __restrict__ fc2W, const float* __restrict__ fc2b,
    float* __restrict__ out) {
    __shared__ float hs_l[64][25];
    __shared__ float sW1[24 * 12], sW2[12 * 8], sb1[12], sg[12], sb[12], sb2[8];
    int tid = threadIdx.x;
    int brow = blockIdx.x * 64;
    for (int i = tid; i < 288; i += 256) sW1[i] = fc1W[i];
    if (tid < 96) sW2[tid] = fc2W[tid];
    if (tid < 12) {
        sb1[tid] = fc1b[tid];
        sg[tid] = lng[tid];
        sb[tid] = lnb[tid];
    }
    if (tid < 8) sb2[tid] = fc2b[tid];
    if (tid < 192) {
        int r = tid / 3;
        int g = tid - r * 3;
        int n = brow + r;
        if (n < NN) {
            const uint4* hrow = (const uint4*)hb;
            int e0 = rowstart[n], e1 = rowstart[n + 1];
            float acc[8] = {};
            int e = e0;
            for (; e + 8 <= e1; e += 8) {
                uint4 u[8];
#pragma unroll
                for (int k = 0; k < 8; k++) u[k] = hrow[(size_t)csr2[e + k] * 3 + g];
#pragma unroll
                for (int k = 0; k < 8; k++) {
                    float f[8];
                    unpk8(u[k], f);
#pragma unroll
                    for (int j = 0; j < 8; j++) acc[j] += f[j];
                }
            }
            for (; e < e1; e++) {
                uint4 u = hrow[(size_t)csr2[e] * 3 + g];
                float f[8];
                unpk8(u, f);
#pragma unroll
                for (int j = 0; j < 8; j++) acc[j] += f[j];
            }
            {
                uint4 u = hrow[(size_t)n * 3 + g];
                float f[8];
                unpk8(u, f);
#pragma unroll
                for (int j = 0; j < 8; j++) acc[j] += f[j];
            }
            float d = dis[n];
#pragma unroll
            for (int j = 0; j < 8; j++) {
                int q = g * 8 + j;
                hs_l[r][q] = fmaxf(acc[j] * d * bnsc[q] + bnsh[q], 0.f);
            }
        }
    }
    __syncthreads();
    if (tid >= 64) return;
    int n = brow + tid;
    if (n >= NN) return;
    float z[12];
#pragma unroll
    for (int j = 0; j < 12; j++) {
        float a = sb1[j];
#pragma unroll
        for (int k = 0; k < 24; k++) a += hs_l[tid][k] * sW1[k * 12 + j];
        z[j] = a;
    }
    float s = 0.f, q = 0.f;
#pragma unroll
    for (int j = 0; j < 12; j++) {
        s += z[j];
        q += z[j] * z[j];
    }
    float m = s * (1.f / 12.f);
    float var = q * (1.f / 12.f) - m * m;
    float rs = rsqrtf(var + EPSL);
#pragma unroll
    for (int j = 0; j < 12; j++) z[j] = fmaxf((z[j] - m) * rs * sg[j] + sb[j], 0.f);
    float o[8];
#pragma unroll
    for (int c = 0; c < 8; c++) {
        float a = sb2[c];
#pragma unroll
        for (int j = 0; j < 12; j++) a += z[j] * sW2[j * 8 + c];
        o[c] = a;
    }
    float4* op = (float4*)(out + (size_t)n * 8);
    op[0] = make_float4(o[0], o[1], o[2], o[3]);
    op[1] = make_float4(o[4], o[5], o[6], o[7]);
}

// ---------------- launch ----------------
extern "C" void kernel_launch(void* const* d_in, const int* in_sizes, int n_in,
                              void* d_out, int out_size, void* d_ws, size_t ws_size,
                              hipStream_t stream) {
    const float* x = (const float*)d_in[0];
    const int* ei = (const int*)d_in[1];
    const float* ln_g = (const float*)d_in[2];
    const float* ln_b = (const float*)d_in[3];
    const float* W1 = (const float*)d_in[4];
    const float* b1 = (const float*)d_in[5];
    const float* bn1_g = (const float*)d_in[6];
    const float* bn1_b = (const float*)d_in[7];
    const float* bn1_m = (const float*)d_in[8];
    const float* bn1_v = (const float*)d_in[9];
    const float* W2 = (const float*)d_in[10];
    const float* b2 = (const float*)d_in[11];
    const float* bn2_g = (const float*)d_in[12];
    const float* bn2_b = (const float*)d_in[13];
    const float* bn2_m = (const float*)d_in[14];
    const float* bn2_v = (const float*)d_in[15];
    const float* W3 = (const float*)d_in[16];
    const float* b3 = (const float*)d_in[17];
    const float* bn3_g = (const float*)d_in[18];
    const float* bn3_b = (const float*)d_in[19];
    const float* bn3_m = (const float*)d_in[20];
    const float* bn3_v = (const float*)d_in[21];
    const float* fc1_W = (const float*)d_in[22];
    const float* fc1_b = (const float*)d_in[23];
    const float* lnc_g = (const float*)d_in[24];
    const float* lnc_b = (const float*)d_in[25];
    const float* fc2_W = (const float*)d_in[26];
    const float* fc2_b = (const float*)d_in[27];

    char* w = (char*)d_ws;
    auto alloc = [&](size_t bytes) {
        char* p = w;
        w += (bytes + 255) & ~(size_t)255;
        return p;
    };
    int* bh = (int*)alloc((size_t)SB * NBUK * 4);
    int* bb = (int*)alloc((size_t)SB * NBUK * 4);  // [blk][bucket]
    int* btxg = (int*)alloc((NBUK + 1) * 4);
    int* rowstart = (int*)alloc((NN + 1) * 4);
    float* dis = (float*)alloc(NN * 4);
    float* bnsc = (float*)alloc(1024);
    float* bnsh = (float*)alloc(1024);
    uint* csr = (uint*)alloc((size_t)NE * 4);      // staged (d_local, src) pairs
    ushort* csr2 = (ushort*)alloc((size_t)NE * 2); // compacted src-only
    ushort* hb = (ushort*)alloc((size_t)NN * F1 * 2);  // gemm outputs (·dis)
    ushort* ag = (ushort*)alloc((size_t)NN * F1 * 2);  // agg outputs
    ushort* Wh = (ushort*)alloc(3072 * 8 * 2);
    ushort* Wl = (ushort*)alloc(3072 * 8 * 2);

    k_prephist<<<13 + SB, 512, 0, stream>>>(W1, Wh, Wl, b1, bn1_g, bn1_b, bn1_m, bn1_v,
                                            b2, bn2_g, bn2_b, bn2_m, bn2_v, b3, bn3_g,
                                            bn3_b, bn3_m, bn3_v, bnsc, bnsh, ei, bh);
    k_scanB3<<<NBUK, 256, 0, stream>>>(bh, bb, btxg);
    k_scatterB<<<SB, 512, 0, stream>>>(ei, bb, csr);
    k_sortb<<<NBUK, 256, 0, stream>>>(btxg, csr, csr2, rowstart, dis);
    k_gemm1m<<<(NN + 63) / 64, 768, 0, stream>>>(x, dis, ln_g, ln_b, Wh, Wl, hb);
    k_agg<12><<<(NN * 12 + 255) / 256, 256, 0, stream>>>(hb, csr2, rowstart, dis, bnsc,
                                                         bnsh, ag);
    k_gemm2<<<(NN + 63) / 64, 256, 0, stream>>>(ag, W2, dis, hb);
    k_agg<6><<<(NN * 6 + 255) / 256, 256, 0, stream>>>(hb, csr2, rowstart, dis,
                                                       bnsc + F1, bnsh + F1, ag);
    k_gemm3<<<(NN + 127) / 128, 256, 0, stream>>>(ag, W3, dis, hb);
    k_aggcls<<<(NN + 63) / 64, 256, 0, stream>>>(hb, csr2, rowstart, dis,
                                                 bnsc + F1 + F2, bnsh + F1 + F2, fc1_W,
                                                 fc1_b, lnc_g, lnc_b, fc2_W, fc2_b,
                                                 (float*)d_out);
}